// Round 18
// baseline (64.917 us; speedup 1.0000x reference)
//
#include <hip/hip_runtime.h>

#define NB 4
#define SEQ 4096
#define EMB 768
#define AD 64
#define BS (NB*SEQ)
#define CHK 16   // kv tiles (of 64) per chunk

typedef short short8 __attribute__((ext_vector_type(8)));
typedef float f32x4 __attribute__((ext_vector_type(4)));
typedef int   i32x2 __attribute__((ext_vector_type(2)));
typedef unsigned short u16;

__device__ __forceinline__ u16 f2bf(float f) {
  union { float f; unsigned u; } v; v.f = f;
  unsigned u = v.u;
  unsigned r = (u + 0x7FFFu + ((u >> 16) & 1u)) >> 16;  // RNE
  return (u16)r;
}

__device__ __forceinline__ float bf2f(u16 b) {
  union { unsigned u; float f; } v; v.u = ((unsigned)b) << 16;
  return v.f;
}

__device__ __forceinline__ unsigned cvt_pk_bf16(float lo, float hi) {
  unsigned r;
  asm("v_cvt_pk_bf16_f32 %0, %1, %2" : "=v"(r) : "v"(lo), "v"(hi));
  return r;
}

__device__ __forceinline__ f32x4 mfma16(short8 a, short8 b, f32x4 c) {
  return __builtin_amdgcn_mfma_f32_16x16x32_bf16(a, b, c, 0, 0, 0);
}

// async global->LDS, 16B per lane; LDS dest = uniform base + lane*16
__device__ __forceinline__ void gload16(const u16* g, u16* l) {
  __builtin_amdgcn_global_load_lds(
      (const __attribute__((address_space(1))) unsigned*)g,
      (__attribute__((address_space(3))) unsigned*)l, 16, 0, 0);
}

__device__ __forceinline__ float xor16_max(float x) {
#if __has_builtin(__builtin_amdgcn_permlane16_swap)
  i32x2 r = __builtin_amdgcn_permlane16_swap(__float_as_int(x), __float_as_int(x), false, false);
  return fmaxf(__int_as_float(r[0]), __int_as_float(r[1]));
#else
  return fmaxf(x, __shfl_xor(x, 16));
#endif
}
__device__ __forceinline__ float xor16_sum(float x) {
#if __has_builtin(__builtin_amdgcn_permlane16_swap)
  i32x2 r = __builtin_amdgcn_permlane16_swap(__float_as_int(x), __float_as_int(x), false, false);
  return __int_as_float(r[0]) + __int_as_float(r[1]);
#else
  return x + __shfl_xor(x, 16);
#endif
}
__device__ __forceinline__ float xor32_max(float x) {
#if __has_builtin(__builtin_amdgcn_permlane32_swap)
  i32x2 r = __builtin_amdgcn_permlane32_swap(__float_as_int(x), __float_as_int(x), false, false);
  return fmaxf(__int_as_float(r[0]), __int_as_float(r[1]));
#else
  return fmaxf(x, __shfl_xor(x, 32));
#endif
}
__device__ __forceinline__ float xor32_sum(float x) {
#if __has_builtin(__builtin_amdgcn_permlane32_swap)
  i32x2 r = __builtin_amdgcn_permlane32_swap(__float_as_int(x), __float_as_int(x), false, false);
  return __int_as_float(r[0]) + __int_as_float(r[1]);
#else
  return x + __shfl_xor(x, 32);
#endif
}

// ---------------- Kernel 0: weight transpose + bf16 cast (PASSING) ----------
// Wt[(m*64 + col)*768 + e] = W_m[e*64 + col]
__global__ void wt_kernel(const float* __restrict__ Wq, const float* __restrict__ Wk,
                          const float* __restrict__ Wv, u16* __restrict__ Wt) {
  int idx = blockIdx.x * 256 + threadIdx.x;
  if (idx >= 3 * AD * EMB) return;
  int m   = idx / (AD * EMB);
  int rem = idx - m * (AD * EMB);
  int col = rem / EMB;
  int e   = rem - col * EMB;
  const float* W = (m == 0) ? Wq : (m == 1) ? Wk : Wv;
  Wt[idx] = f2bf(W[e * AD + col]);
}

// ---------------- Kernel 1: QKV projection, LDS-staged GEMM (R17) -----------
__global__ __launch_bounds__(512) void proj_kernel(const float* __restrict__ emb,
                                                   const u16* __restrict__ Wt,
                                                   u16* __restrict__ Q, u16* __restrict__ K,
                                                   u16* __restrict__ Vt) {
  const int w = threadIdx.x >> 6;
  const int lane = threadIdx.x & 63;
  const int g = lane >> 4, c = lane & 15;
  const int wr = w & 1;                 // row group (16 rows)
  const int cq = w >> 1;                // col quarter (3 fragments)
  const int rbase = blockIdx.x * 32;

  __shared__ __align__(16) char ebuf[2][2][4096];    // [buf][kk][32 rows][128B], key row&7
  __shared__ __align__(16) char wbuf[2][2][12288];   // [buf][kk][192 cols][64B], key (col&3)^((col>>2)&3)
  __shared__ u16 t[32][65];                          // V transpose staging

  const int r8 = lane >> 3, j8 = lane & 7;        // emb staging decomposition
  const int c4 = lane >> 2, j4 = lane & 3;        // wt staging decomposition

  f32x4 acc[3];
#pragma unroll
  for (int fi = 0; fi < 3; ++fi)
#pragma unroll
    for (int r = 0; r < 4; ++r) acc[fi][r] = 0.f;

#define PSTAGE(bufi, kk, kt) do {                                              \
    { const int col = w * 16 + c4;                                             \
      const int kc = (col & 3) ^ ((col >> 2) & 3);                             \
      gload16(Wt + (size_t)col * EMB + (kt) * 32 + ((j4 ^ kc) << 3),           \
              (u16*)(wbuf[bufi][kk] + w * 1024)); }                            \
    if (w < 4) {                                                               \
      gload16((const u16*)(emb + (size_t)(rbase + w * 8 + r8) * EMB            \
                           + (kt) * 32 + ((j8 ^ r8) << 2)),                    \
              (u16*)(ebuf[bufi][kk] + w * 1024));                              \
    } else {                                                                   \
      const int col = (4 + w) * 16 + c4;                                       \
      const int kc = (col & 3) ^ ((col >> 2) & 3);                             \
      gload16(Wt + (size_t)col * EMB + (kt) * 32 + ((j4 ^ kc) << 3),           \
              (u16*)(wbuf[bufi][kk] + (4 + w) * 1024));                        \
    }                                                                          \
  } while (0)

  PSTAGE(0, 0, 0);
  PSTAGE(0, 1, 1);
  __syncthreads();

  int cur = 0;
  for (int it = 0; it < 12; ++it) {
    if (it + 1 < 12) {
      PSTAGE(cur ^ 1, 0, 2 * it + 2);
      PSTAGE(cur ^ 1, 1, 2 * it + 3);
    }

#pragma unroll
    for (int kk = 0; kk < 2; ++kk) {
      const char* eb = ebuf[cur][kk];
      const int arow = (wr * 16 + c) * 128;
      const int sw = (c & 7) << 4;
      float4 fa0 = *(const float4*)(eb + arow + ((g * 32) ^ sw));
      float4 fa1 = *(const float4*)(eb + arow + ((g * 32 + 16) ^ sw));
      union { unsigned u[4]; short8 v; } uu;
      uu.u[0] = cvt_pk_bf16(fa0.x, fa0.y);
      uu.u[1] = cvt_pk_bf16(fa0.z, fa0.w);
      uu.u[2] = cvt_pk_bf16(fa1.x, fa1.y);
      uu.u[3] = cvt_pk_bf16(fa1.z, fa1.w);
      const short8 af = uu.v;

      const char* wb = wbuf[cur][kk];
#pragma unroll
      for (int fi = 0; fi < 3; ++fi) {
        const int fg = cq * 3 + fi;
        const int col = (fg >> 2) * 64 + (fg & 3) * 16 + c;
        const int kc = (col & 3) ^ ((col >> 2) & 3);
        short8 bf = *(const short8*)(wb + col * 64 + ((g ^ kc) << 4));
        acc[fi] = mfma16(af, bf, acc[fi]);
      }
    }

    __syncthreads();
    cur ^= 1;
  }

#pragma unroll
  for (int fi = 0; fi < 3; ++fi) {
    const int fg = cq * 3 + fi;
    const int m = fg >> 2, cf = fg & 3;
    const int col = cf * 16 + c;
#pragma unroll
    for (int r = 0; r < 4; ++r) {
      const int rloc = wr * 16 + g * 4 + r;
      const size_t grow = (size_t)(rbase + rloc);
      const float v = acc[fi][r];
      if (m == 0)      Q[grow * AD + col] = f2bf(v * 0.125f);  // fold 1/sqrt(64)
      else if (m == 1) K[grow * AD + col] = f2bf(v);
      else             t[rloc][col] = f2bf(v);
    }
  }
  __syncthreads();
  const int bb = blockIdx.x >> 7;             // 128 blocks per batch
  const int sb = (blockIdx.x & 127) * 32;
  const int s = threadIdx.x & 31;
  const int d0 = threadIdx.x >> 5;            // 0..15
#pragma unroll
  for (int it = 0; it < 4; ++it) {
    const int d = it * 16 + d0;
    Vt[(size_t)(bb * AD + d) * SEQ + sb + s] = t[s][d];
  }
#undef PSTAGE
}

// ---------------- Kernel 2: flash attention partials (2 waves x 32 q) -------
// Block = 64 q-rows x one 16-tile chunk; 128 threads = 2 waves; each wave
// owns TWO 16-q groups (a: q0..q0+15, b: +16). K/V ds_reads loaded once feed
// both groups' MFMAs (halves LDS traffic). Per-group logic identical to R17.
__global__ __launch_bounds__(128, 2) void flash_part(const u16* __restrict__ Q,
                                                     const u16* __restrict__ K,
                                                     const u16* __restrict__ Vt,
                                                     u16* __restrict__ opart,
                                                     float* __restrict__ ml) {
  const int bx = blockIdx.x;
  const int b = bx & 3;
  const int u = bx >> 2;
  int bq, c;
  if (u < 16)       { bq = 16 + u;        c = 0; }   // 16-tile blocks first
  else if (u < 32)  { bq = 32 + (u - 16); c = 0; }
  else if (u < 48)  { bq = 32 + (u - 32); c = 1; }
  else if (u < 64)  { bq = 48 + (u - 48); c = 0; }
  else if (u < 80)  { bq = 48 + (u - 64); c = 1; }
  else if (u < 96)  { bq = 48 + (u - 80); c = 2; }
  else { int d = u - 96; bq = (d >> 4) * 16 + 15 - (d & 15); c = d >> 4; }
  const int t0 = c * CHK;
  const int tend = (c == (bq >> 4)) ? (bq + 1) : (t0 + CHK);  // diag: up to tile bq

  const int w = threadIdx.x >> 6;             // 0..1
  const int lane = threadIdx.x & 63;
  const int g = lane >> 4, cl = lane & 15;
  const int r8 = lane >> 3, c16 = lane & 7;   // staging decomposition
  const int q0 = bq * 64 + w * 32;            // group a base; group b = q0+16

  const u16* Qb = Q + (size_t)b * SEQ * AD;
  const u16* Kb = K + (size_t)b * SEQ * AD;
  const u16* Vb = Vt + (size_t)b * AD * SEQ;

  __shared__ __align__(16) u16 kbuf[2][64 * 64];
  __shared__ __align__(16) u16 vbuf[2][64 * 64];
  __shared__ __align__(16) u16 plds_all[2][2][16 * 64];   // [wave][group]
  char* pldsA = (char*)plds_all[w][0];
  char* pldsB = (char*)plds_all[w][1];
  const int swz = (cl & 7) << 4;
  const int prow = cl * 128;
  const int fsw = (cl & 7);                    // fragment-read row swizzle key

  const short8 qf0a = *(const short8*)(Qb + (size_t)(q0 + cl) * AD + g * 8);
  const short8 qf1a = *(const short8*)(Qb + (size_t)(q0 + cl) * AD + 32 + g * 8);
  const short8 qf0b = *(const short8*)(Qb + (size_t)(q0 + 16 + cl) * AD + g * 8);
  const short8 qf1b = *(const short8*)(Qb + (size_t)(q0 + 16 + cl) * AD + 32 + g * 8);

  float mrow_a = -INFINITY, lrow_a = 0.f;
  float mrow_b = -INFINITY, lrow_b = 0.f;
  f32x4 oa[4], ob[4];
#pragma unroll
  for (int cf = 0; cf < 4; cf++)
#pragma unroll
    for (int r = 0; r < 4; r++) { oa[cf][r] = 0.f; ob[cf][r] = 0.f; }

  // wave w stages rows [w*32, w*32+32) of K (kv rows) and V (d rows): 4+4 gloads
#define STAGE(bufi, tt) do {                                                   \
    const int kvb = (tt) * 64;                                                 \
    _Pragma("unroll")                                                          \
    for (int rr = 0; rr < 4; ++rr) {                                           \
      const int row0 = w * 32 + rr * 8 + r8;                                   \
      gload16(Kb + (size_t)(kvb + row0) * AD + ((c16 ^ r8) << 3),              \
              &kbuf[bufi][(w * 32 + rr * 8) * 64]);                            \
      gload16(Vb + (size_t)row0 * SEQ + kvb + ((c16 ^ r8) << 3),               \
              &vbuf[bufi][(w * 32 + rr * 8) * 64]);                            \
    }                                                                          \
  } while (0)

  STAGE(0, t0);
  __syncthreads();

  int cur = 0;
  for (int t = t0; t < tend; ++t) {
    const int kv0 = t * 64;
    if (t + 1 < tend) STAGE(cur ^ 1, t + 1);

    const char* kb = (const char*)kbuf[cur];
    const char* vb = (const char*)vbuf[cur];

    short8 kf0[4], kf1[4];
#pragma unroll
    for (int cf = 0; cf < 4; cf++) {
      const int kr = (cf * 16 + cl) * 128;
      kf0[cf] = *(const short8*)(kb + kr + ((g ^ fsw) << 4));
      kf1[cf] = *(const short8*)(kb + kr + (((4 + g) ^ fsw) << 4));
    }

    f32x4 s4a[4], s4b[4];
#pragma unroll
    for (int cf = 0; cf < 4; cf++) {
      f32x4 za; za[0] = za[1] = za[2] = za[3] = 0.f;
      f32x4 zb; zb[0] = zb[1] = zb[2] = zb[3] = 0.f;
      za = mfma16(kf0[cf], qf0a, za);
      s4a[cf] = mfma16(kf1[cf], qf1a, za);
      zb = mfma16(kf0[cf], qf0b, zb);
      s4b[cf] = mfma16(kf1[cf], qf1b, zb);
    }

    if (t == bq) {
#pragma unroll
      for (int cf = 0; cf < 4; cf++) {
        const int kvb2 = kv0 + cf * 16 + g * 4;
#pragma unroll
        for (int r = 0; r < 4; r++) {
          s4a[cf][r] = (kvb2 + r <= q0 + cl)      ? s4a[cf][r] : -INFINITY;
          s4b[cf][r] = (kvb2 + r <= q0 + 16 + cl) ? s4b[cf][r] : -INFINITY;
        }
      }
    }

    // tile maxes (independent per group)
    float tma[4], tmb[4];
#pragma unroll
    for (int cf = 0; cf < 4; cf++) {
      tma[cf] = fmaxf(fmaxf(s4a[cf][0], s4a[cf][1]), fmaxf(s4a[cf][2], s4a[cf][3]));
      tmb[cf] = fmaxf(fmaxf(s4b[cf][0], s4b[cf][1]), fmaxf(s4b[cf][2], s4b[cf][3]));
    }
    float mta = fmaxf(fmaxf(tma[0], tma[1]), fmaxf(tma[2], tma[3]));
    float mtb = fmaxf(fmaxf(tmb[0], tmb[1]), fmaxf(tmb[2], tmb[3]));
    mta = xor16_max(mta); mta = xor32_max(mta);
    mtb = xor16_max(mtb); mtb = xor32_max(mtb);

    // defer-max: rescale both groups when either grew by > 8 (exact either way)
    if (!__all((mta <= mrow_a + 8.0f) && (mtb <= mrow_b + 8.0f))) {
      const float mna = fmaxf(mrow_a, mta);
      const float corr_a = __expf(mrow_a - mna);
      mrow_a = mna; lrow_a *= corr_a;
      const float mnb = fmaxf(mrow_b, mtb);
      const float corr_b = __expf(mrow_b - mnb);
      mrow_b = mnb; lrow_b *= corr_b;
      float cba[4], cbb[4];
#pragma unroll
      for (int r = 0; r < 4; r++) {
        cba[r] = __shfl(corr_a, g * 20 + r);
        cbb[r] = __shfl(corr_b, g * 20 + r);
      }
#pragma unroll
      for (int cf = 0; cf < 4; cf++) {
        oa[cf][0] *= cba[0]; oa[cf][1] *= cba[1];
        oa[cf][2] *= cba[2]; oa[cf][3] *= cba[3];
        ob[cf][0] *= cbb[0]; ob[cf][1] *= cbb[1];
        ob[cf][2] *= cbb[2]; ob[cf][3] *= cbb[3];
      }
    }

    // P = exp(S - m): per group, pack to its plds region
    float rsa = 0.f, rsb = 0.f;
#pragma unroll
    for (int cf = 0; cf < 4; cf++) {
      const float a0 = __expf(s4a[cf][0] - mrow_a);
      const float a1 = __expf(s4a[cf][1] - mrow_a);
      const float a2 = __expf(s4a[cf][2] - mrow_a);
      const float a3 = __expf(s4a[cf][3] - mrow_a);
      rsa += (a0 + a1) + (a2 + a3);
      uint2 va;
      va.x = cvt_pk_bf16(a0, a1);
      va.y = cvt_pk_bf16(a2, a3);
      *(uint2*)(pldsA + prow + (((cf * 32) + (g * 8)) ^ swz)) = va;
      const float b0 = __expf(s4b[cf][0] - mrow_b);
      const float b1 = __expf(s4b[cf][1] - mrow_b);
      const float b2 = __expf(s4b[cf][2] - mrow_b);
      const float b3 = __expf(s4b[cf][3] - mrow_b);
      rsb += (b0 + b1) + (b2 + b3);
      uint2 vbw;
      vbw.x = cvt_pk_bf16(b0, b1);
      vbw.y = cvt_pk_bf16(b2, b3);
      *(uint2*)(pldsB + prow + (((cf * 32) + (g * 8)) ^ swz)) = vbw;
    }
    rsa = xor16_sum(rsa); rsa = xor32_sum(rsa); lrow_a += rsa;
    rsb = xor16_sum(rsb); rsb = xor32_sum(rsb); lrow_b += rsb;

    // Fence: uint2-typed P writes vs short8-typed reads (TBAA no-alias)
    asm volatile("" ::: "memory");

    // PV: V fragment loaded once feeds BOTH groups
#pragma unroll
    for (int f = 0; f < 2; ++f) {
      const short8 pfA = *(const short8*)(pldsA + prow + ((f * 64 + g * 16) ^ swz));
      const short8 pfB = *(const short8*)(pldsB + prow + ((f * 64 + g * 16) ^ swz));
#pragma unroll
      for (int cf = 0; cf < 4; cf++) {
        const int vr = (cf * 16 + cl) * 128;
        const short8 vfa = *(const short8*)(vb + vr + (((f * 4 + g) ^ fsw) << 4));
        oa[cf] = mfma16(pfA, vfa, oa[cf]);
        ob[cf] = mfma16(pfB, vfa, ob[cf]);
      }
    }

    __syncthreads();
    cur ^= 1;
  }

  // ---- write both groups' partial slots ----
  const int qga = bq * 4 + w * 2;
  const int qgb = qga + 1;
  const int k2 = qga >> 6;                    // same 64-group for a and b
  const int slota = b * 640 + 32 * k2 * (k2 + 1) + (qga & 63) * (k2 + 1) + c;
  const int slotb = b * 640 + 32 * k2 * (k2 + 1) + (qgb & 63) * (k2 + 1) + c;

  if (lane < 16) {
    ml[(size_t)slota * 32 + cl * 2 + 0] = mrow_a;
    ml[(size_t)slota * 32 + cl * 2 + 1] = lrow_a;
    ml[(size_t)slotb * 32 + cl * 2 + 0] = mrow_b;
    ml[(size_t)slotb * 32 + cl * 2 + 1] = lrow_b;
  }
#pragma unroll
  for (int cf = 0; cf < 4; cf++)
#pragma unroll
    for (int r = 0; r < 4; r++) {
      opart[(size_t)slota * 1024 + (g * 4 + r) * 64 + cf * 16 + cl] = f2bf(oa[cf][r]);
      opart[(size_t)slotb * 1024 + (g * 4 + r) * 64 + cf * 16 + cl] = f2bf(ob[cf][r]);
    }
#undef STAGE
}

// ---------------- Kernel 3: combine partials (bf16 opart, R17) --------------
__global__ __launch_bounds__(256) void combine_kernel(const u16* __restrict__ opart,
                                                      const float* __restrict__ ml,
                                                      float* __restrict__ out) {
  const int tid = threadIdx.x;
  const int row = blockIdx.x * 16 + (tid >> 4);   // 0..16383
  const int d = (tid & 15) * 4;
  const int b = row >> 12;
  const int rowb = row & 4095;
  const int qg = rowb >> 4;
  const int r = rowb & 15;
  const int k2 = qg >> 6;
  const int nc = k2 + 1;
  const int sbase = b * 640 + 32 * k2 * (k2 + 1) + (qg & 63) * nc;

  float M = -INFINITY;
  float ms[4], ls[4];
  for (int cc = 0; cc < nc; cc++) {
    ms[cc] = ml[(size_t)(sbase + cc) * 32 + r * 2 + 0];
    ls[cc] = ml[(size_t)(sbase + cc) * 32 + r * 2 + 1];
    M = fmaxf(M, ms[cc]);
  }
  float L = 0.f;
  float4 acc = {0.f, 0.f, 0.f, 0.f};
  for (int cc = 0; cc < nc; cc++) {
    const float wgt = __expf(ms[cc] - M);
    L += ls[cc] * wgt;
    ushort4 ov = *(const ushort4*)(opart + (size_t)(sbase + cc) * 1024 + r * 64 + d);
    acc.x += bf2f(ov.x) * wgt; acc.y += bf2f(ov.y) * wgt;
    acc.z += bf2f(ov.z) * wgt; acc.w += bf2f(ov.w) * wgt;
  }
  const float inv = 1.0f / L;
  float4 res;
  res.x = rintf(acc.x * inv * 1.0e4f) * 1.0e-4f;
  res.y = rintf(acc.y * inv * 1.0e4f) * 1.0e-4f;
  res.z = rintf(acc.z * inv * 1.0e4f) * 1.0e-4f;
  res.w = rintf(acc.w * inv * 1.0e4f) * 1.0e-4f;
  *(float4*)(out + (size_t)row * AD + d) = res;
}

extern "C" void kernel_launch(void* const* d_in, const int* in_sizes, int n_in,
                              void* d_out, int out_size, void* d_ws, size_t ws_size,
                              hipStream_t stream) {
  const float* emb = (const float*)d_in[0];
  const float* Wq  = (const float*)d_in[1];
  const float* Wk  = (const float*)d_in[2];
  const float* Wv  = (const float*)d_in[3];
  float* out = (float*)d_out;

  char* ws = (char*)d_ws;
  u16* Wt = (u16*)ws;                               // 294912 B
  u16* Q  = (u16*)(ws + 294912);                    // 2 MiB each
  u16* K  = Q + (size_t)BS * AD;
  u16* Vt = K + (size_t)BS * AD;
  u16* opart = (u16*)(ws + 294912 + 3 * (size_t)BS * AD * 2);  // 2560*2KB bf16
  float* ml  = (float*)(ws + 294912 + 3 * (size_t)BS * AD * 2
                        + (size_t)2560 * 1024 * 2);            // 2560*128B

  wt_kernel<<<(3 * AD * EMB + 255) / 256, 256, 0, stream>>>(Wq, Wk, Wv, Wt);
  proj_kernel<<<BS / 32, 512, 0, stream>>>(emb, Wt, Q, K, Vt);
  flash_part<<<640, 128, 0, stream>>>(Q, K, Vt, opart, ml);
  combine_kernel<<<BS / 16, 256, 0, stream>>>(opart, ml, out);
}

// Round 19
// 57.774 us; speedup vs baseline: 1.1236x; 1.1236x over previous
//
#include <hip/hip_runtime.h>

#define NB 4
#define SEQ 4096
#define EMB 768
#define AD 64
#define BS (NB*SEQ)
#define CHK 16   // kv tiles (of 64) per chunk

typedef short short8 __attribute__((ext_vector_type(8)));
typedef float f32x4 __attribute__((ext_vector_type(4)));
typedef int   i32x2 __attribute__((ext_vector_type(2)));
typedef unsigned short u16;

__device__ __forceinline__ u16 f2bf(float f) {
  union { float f; unsigned u; } v; v.f = f;
  unsigned u = v.u;
  unsigned r = (u + 0x7FFFu + ((u >> 16) & 1u)) >> 16;  // RNE
  return (u16)r;
}

__device__ __forceinline__ float bf2f(u16 b) {
  union { unsigned u; float f; } v; v.u = ((unsigned)b) << 16;
  return v.f;
}

__device__ __forceinline__ unsigned cvt_pk_bf16(float lo, float hi) {
  unsigned r;
  asm("v_cvt_pk_bf16_f32 %0, %1, %2" : "=v"(r) : "v"(lo), "v"(hi));
  return r;
}

__device__ __forceinline__ f32x4 mfma16(short8 a, short8 b, f32x4 c) {
  return __builtin_amdgcn_mfma_f32_16x16x32_bf16(a, b, c, 0, 0, 0);
}

// async global->LDS, 16B per lane; LDS dest = uniform base + lane*16
__device__ __forceinline__ void gload16(const u16* g, u16* l) {
  __builtin_amdgcn_global_load_lds(
      (const __attribute__((address_space(1))) unsigned*)g,
      (__attribute__((address_space(3))) unsigned*)l, 16, 0, 0);
}

__device__ __forceinline__ float xor16_max(float x) {
#if __has_builtin(__builtin_amdgcn_permlane16_swap)
  i32x2 r = __builtin_amdgcn_permlane16_swap(__float_as_int(x), __float_as_int(x), false, false);
  return fmaxf(__int_as_float(r[0]), __int_as_float(r[1]));
#else
  return fmaxf(x, __shfl_xor(x, 16));
#endif
}
__device__ __forceinline__ float xor16_sum(float x) {
#if __has_builtin(__builtin_amdgcn_permlane16_swap)
  i32x2 r = __builtin_amdgcn_permlane16_swap(__float_as_int(x), __float_as_int(x), false, false);
  return __int_as_float(r[0]) + __int_as_float(r[1]);
#else
  return x + __shfl_xor(x, 16);
#endif
}
__device__ __forceinline__ float xor32_max(float x) {
#if __has_builtin(__builtin_amdgcn_permlane32_swap)
  i32x2 r = __builtin_amdgcn_permlane32_swap(__float_as_int(x), __float_as_int(x), false, false);
  return fmaxf(__int_as_float(r[0]), __int_as_float(r[1]));
#else
  return fmaxf(x, __shfl_xor(x, 32));
#endif
}
__device__ __forceinline__ float xor32_sum(float x) {
#if __has_builtin(__builtin_amdgcn_permlane32_swap)
  i32x2 r = __builtin_amdgcn_permlane32_swap(__float_as_int(x), __float_as_int(x), false, false);
  return __int_as_float(r[0]) + __int_as_float(r[1]);
#else
  return x + __shfl_xor(x, 32);
#endif
}

// ---------------- Kernel 0: weight transpose + bf16 cast (PASSING) ----------
// Wt[(m*64 + col)*768 + e] = W_m[e*64 + col]
__global__ void wt_kernel(const float* __restrict__ Wq, const float* __restrict__ Wk,
                          const float* __restrict__ Wv, u16* __restrict__ Wt) {
  int idx = blockIdx.x * 256 + threadIdx.x;
  if (idx >= 3 * AD * EMB) return;
  int m   = idx / (AD * EMB);
  int rem = idx - m * (AD * EMB);
  int col = rem / EMB;
  int e   = rem - col * EMB;
  const float* W = (m == 0) ? Wq : (m == 1) ? Wk : Wv;
  Wt[idx] = f2bf(W[e * AD + col]);
}

// ---------------- Kernel 1: QKV projection, LDS-staged GEMM (R17) -----------
__global__ __launch_bounds__(512) void proj_kernel(const float* __restrict__ emb,
                                                   const u16* __restrict__ Wt,
                                                   u16* __restrict__ Q, u16* __restrict__ K,
                                                   u16* __restrict__ Vt) {
  const int w = threadIdx.x >> 6;
  const int lane = threadIdx.x & 63;
  const int g = lane >> 4, c = lane & 15;
  const int wr = w & 1;                 // row group (16 rows)
  const int cq = w >> 1;                // col quarter (3 fragments)
  const int rbase = blockIdx.x * 32;

  __shared__ __align__(16) char ebuf[2][2][4096];    // [buf][kk][32 rows][128B], key row&7
  __shared__ __align__(16) char wbuf[2][2][12288];   // [buf][kk][192 cols][64B], key (col&3)^((col>>2)&3)
  __shared__ u16 t[32][65];                          // V transpose staging

  const int r8 = lane >> 3, j8 = lane & 7;        // emb staging decomposition
  const int c4 = lane >> 2, j4 = lane & 3;        // wt staging decomposition

  f32x4 acc[3];
#pragma unroll
  for (int fi = 0; fi < 3; ++fi)
#pragma unroll
    for (int r = 0; r < 4; ++r) acc[fi][r] = 0.f;

#define PSTAGE(bufi, kk, kt) do {                                              \
    { const int col = w * 16 + c4;                                             \
      const int kc = (col & 3) ^ ((col >> 2) & 3);                             \
      gload16(Wt + (size_t)col * EMB + (kt) * 32 + ((j4 ^ kc) << 3),           \
              (u16*)(wbuf[bufi][kk] + w * 1024)); }                            \
    if (w < 4) {                                                               \
      gload16((const u16*)(emb + (size_t)(rbase + w * 8 + r8) * EMB            \
                           + (kt) * 32 + ((j8 ^ r8) << 2)),                    \
              (u16*)(ebuf[bufi][kk] + w * 1024));                              \
    } else {                                                                   \
      const int col = (4 + w) * 16 + c4;                                       \
      const int kc = (col & 3) ^ ((col >> 2) & 3);                             \
      gload16(Wt + (size_t)col * EMB + (kt) * 32 + ((j4 ^ kc) << 3),           \
              (u16*)(wbuf[bufi][kk] + (4 + w) * 1024));                        \
    }                                                                          \
  } while (0)

  PSTAGE(0, 0, 0);
  PSTAGE(0, 1, 1);
  __syncthreads();

  int cur = 0;
  for (int it = 0; it < 12; ++it) {
    if (it + 1 < 12) {
      PSTAGE(cur ^ 1, 0, 2 * it + 2);
      PSTAGE(cur ^ 1, 1, 2 * it + 3);
    }

#pragma unroll
    for (int kk = 0; kk < 2; ++kk) {
      const char* eb = ebuf[cur][kk];
      const int arow = (wr * 16 + c) * 128;
      const int sw = (c & 7) << 4;
      float4 fa0 = *(const float4*)(eb + arow + ((g * 32) ^ sw));
      float4 fa1 = *(const float4*)(eb + arow + ((g * 32 + 16) ^ sw));
      union { unsigned u[4]; short8 v; } uu;
      uu.u[0] = cvt_pk_bf16(fa0.x, fa0.y);
      uu.u[1] = cvt_pk_bf16(fa0.z, fa0.w);
      uu.u[2] = cvt_pk_bf16(fa1.x, fa1.y);
      uu.u[3] = cvt_pk_bf16(fa1.z, fa1.w);
      const short8 af = uu.v;

      const char* wb = wbuf[cur][kk];
#pragma unroll
      for (int fi = 0; fi < 3; ++fi) {
        const int fg = cq * 3 + fi;
        const int col = (fg >> 2) * 64 + (fg & 3) * 16 + c;
        const int kc = (col & 3) ^ ((col >> 2) & 3);
        short8 bf = *(const short8*)(wb + col * 64 + ((g ^ kc) << 4));
        acc[fi] = mfma16(af, bf, acc[fi]);
      }
    }

    __syncthreads();
    cur ^= 1;
  }

#pragma unroll
  for (int fi = 0; fi < 3; ++fi) {
    const int fg = cq * 3 + fi;
    const int m = fg >> 2, cf = fg & 3;
    const int col = cf * 16 + c;
#pragma unroll
    for (int r = 0; r < 4; ++r) {
      const int rloc = wr * 16 + g * 4 + r;
      const size_t grow = (size_t)(rbase + rloc);
      const float v = acc[fi][r];
      if (m == 0)      Q[grow * AD + col] = f2bf(v * 0.125f);  // fold 1/sqrt(64)
      else if (m == 1) K[grow * AD + col] = f2bf(v);
      else             t[rloc][col] = f2bf(v);
    }
  }
  __syncthreads();
  const int bb = blockIdx.x >> 7;             // 128 blocks per batch
  const int sb = (blockIdx.x & 127) * 32;
  const int s = threadIdx.x & 31;
  const int d0 = threadIdx.x >> 5;            // 0..15
#pragma unroll
  for (int it = 0; it < 4; ++it) {
    const int d = it * 16 + d0;
    Vt[(size_t)(bb * AD + d) * SEQ + sb + s] = t[s][d];
  }
#undef PSTAGE
}

// ---------------- Kernel 2: flash attention partials (R17 + occupancy 4) ----
__global__ __launch_bounds__(256, 4) void flash_part(const u16* __restrict__ Q,
                                                     const u16* __restrict__ K,
                                                     const u16* __restrict__ Vt,
                                                     u16* __restrict__ opart,
                                                     float* __restrict__ ml) {
  const int bx = blockIdx.x;
  const int b = bx & 3;
  const int u = bx >> 2;
  int bq, c;
  if (u < 16)       { bq = 16 + u;        c = 0; }   // 16-tile blocks first
  else if (u < 32)  { bq = 32 + (u - 16); c = 0; }
  else if (u < 48)  { bq = 32 + (u - 32); c = 1; }
  else if (u < 64)  { bq = 48 + (u - 48); c = 0; }
  else if (u < 80)  { bq = 48 + (u - 64); c = 1; }
  else if (u < 96)  { bq = 48 + (u - 80); c = 2; }
  else { int d = u - 96; bq = (d >> 4) * 16 + 15 - (d & 15); c = d >> 4; }
  const int t0 = c * CHK;
  const int tend = (c == (bq >> 4)) ? (bq + 1) : (t0 + CHK);  // diag: up to tile bq

  const int w = threadIdx.x >> 6;
  const int lane = threadIdx.x & 63;
  const int g = lane >> 4, cl = lane & 15;
  const int r8 = lane >> 3, c16 = lane & 7;   // staging decomposition
  const int q0 = bq * 64 + w * 16;

  const u16* Qb = Q + (size_t)b * SEQ * AD;
  const u16* Kb = K + (size_t)b * SEQ * AD;
  const u16* Vb = Vt + (size_t)b * AD * SEQ;

  __shared__ __align__(16) u16 kbuf[2][64 * 64];
  __shared__ __align__(16) u16 vbuf[2][64 * 64];
  __shared__ __align__(16) u16 plds_all[4][16 * 64];
  char* plds = (char*)plds_all[w];
  const int swz = (cl & 7) << 4;
  const int prow = cl * 128;
  const int fsw = (cl & 7);                    // fragment-read row swizzle key

  const short8 qf0 = *(const short8*)(Qb + (size_t)(q0 + cl) * AD + g * 8);
  const short8 qf1 = *(const short8*)(Qb + (size_t)(q0 + cl) * AD + 32 + g * 8);

  float mrow = -INFINITY, lrow = 0.f;
  f32x4 o[4];
#pragma unroll
  for (int cf = 0; cf < 4; cf++)
#pragma unroll
    for (int r = 0; r < 4; r++) o[cf][r] = 0.f;

#define STAGE(bufi, tt) do {                                                   \
    const int kvb = (tt) * 64;                                                 \
    const int row0 = w * 16 + r8, row1 = w * 16 + 8 + r8;                      \
    gload16(Kb + (size_t)(kvb + row0) * AD + ((c16 ^ r8) << 3),                \
            &kbuf[bufi][(w * 16) * 64]);                                       \
    gload16(Kb + (size_t)(kvb + row1) * AD + ((c16 ^ r8) << 3),                \
            &kbuf[bufi][(w * 16 + 8) * 64]);                                   \
    gload16(Vb + (size_t)row0 * SEQ + kvb + ((c16 ^ r8) << 3),                 \
            &vbuf[bufi][(w * 16) * 64]);                                       \
    gload16(Vb + (size_t)row1 * SEQ + kvb + ((c16 ^ r8) << 3),                 \
            &vbuf[bufi][(w * 16 + 8) * 64]);                                   \
  } while (0)

  STAGE(0, t0);
  __syncthreads();

  int cur = 0;
  for (int t = t0; t < tend; ++t) {
    const int kv0 = t * 64;
    if (t + 1 < tend) STAGE(cur ^ 1, t + 1);

    const char* kb = (const char*)kbuf[cur];
    const char* vb = (const char*)vbuf[cur];

    short8 kf0[4], kf1[4];
#pragma unroll
    for (int cf = 0; cf < 4; cf++) {
      const int kr = (cf * 16 + cl) * 128;
      kf0[cf] = *(const short8*)(kb + kr + ((g ^ fsw) << 4));
      kf1[cf] = *(const short8*)(kb + kr + (((4 + g) ^ fsw) << 4));
    }

    f32x4 s4[4];
#pragma unroll
    for (int cf = 0; cf < 4; cf++) {
      f32x4 z; z[0] = z[1] = z[2] = z[3] = 0.f;
      z = mfma16(kf0[cf], qf0, z);
      s4[cf] = mfma16(kf1[cf], qf1, z);
    }

    if (t == bq) {
#pragma unroll
      for (int cf = 0; cf < 4; cf++) {
        const int kvb2 = kv0 + cf * 16 + g * 4;
#pragma unroll
        for (int r = 0; r < 4; r++)
          s4[cf][r] = (kvb2 + r <= q0 + cl) ? s4[cf][r] : -INFINITY;
      }
    }

    float tm[4];
#pragma unroll
    for (int cf = 0; cf < 4; cf++)
      tm[cf] = fmaxf(fmaxf(s4[cf][0], s4[cf][1]), fmaxf(s4[cf][2], s4[cf][3]));
    float mt = fmaxf(fmaxf(tm[0], tm[1]), fmaxf(tm[2], tm[3]));
    mt = xor16_max(mt);
    mt = xor32_max(mt);

    if (!__all(mt <= mrow + 8.0f)) {
      const float mn = fmaxf(mrow, mt);
      const float corr = __expf(mrow - mn);
      mrow = mn;
      lrow *= corr;
      float cb[4];
#pragma unroll
      for (int r = 0; r < 4; r++) cb[r] = __shfl(corr, g * 20 + r);
#pragma unroll
      for (int cf = 0; cf < 4; cf++) {
        o[cf][0] *= cb[0]; o[cf][1] *= cb[1];
        o[cf][2] *= cb[2]; o[cf][3] *= cb[3];
      }
    }

    float rs = 0.f;
#pragma unroll
    for (int cf = 0; cf < 4; cf++) {
      const float p0 = __expf(s4[cf][0] - mrow);
      const float p1 = __expf(s4[cf][1] - mrow);
      const float p2 = __expf(s4[cf][2] - mrow);
      const float p3 = __expf(s4[cf][3] - mrow);
      rs += (p0 + p1) + (p2 + p3);
      uint2 val;
      val.x = cvt_pk_bf16(p0, p1);
      val.y = cvt_pk_bf16(p2, p3);
      *(uint2*)(plds + prow + (((cf * 32) + (g * 8)) ^ swz)) = val;
    }
    rs = xor16_sum(rs);
    rs = xor32_sum(rs);
    lrow += rs;

    // Fence: P ds_writes above are uint2-typed, PV ds_reads below are
    // short8-typed -- TBAA says no-alias; keep the RAW pair ordered.
    asm volatile("" ::: "memory");

#pragma unroll
    for (int f = 0; f < 2; ++f) {
      const short8 pf = *(const short8*)(plds + prow + ((f * 64 + g * 16) ^ swz));
#pragma unroll
      for (int cf = 0; cf < 4; cf++) {
        const int vr = (cf * 16 + cl) * 128;
        const short8 vfa = *(const short8*)(vb + vr + (((f * 4 + g) ^ fsw) << 4));
        o[cf] = mfma16(pf, vfa, o[cf]);
      }
    }

    __syncthreads();
    cur ^= 1;
  }

  const int qg = bq * 4 + w;
  const int k2 = qg >> 6;
  const int slot = b * 640 + 32 * k2 * (k2 + 1) + (qg & 63) * (k2 + 1) + c;

  if (lane < 16) {
    ml[(size_t)slot * 32 + cl * 2 + 0] = mrow;
    ml[(size_t)slot * 32 + cl * 2 + 1] = lrow;
  }
#pragma unroll
  for (int cf = 0; cf < 4; cf++)
#pragma unroll
    for (int r = 0; r < 4; r++)
      opart[(size_t)slot * 1024 + (g * 4 + r) * 64 + cf * 16 + cl] = f2bf(o[cf][r]);
#undef STAGE
}

// ---------------- Kernel 3: combine partials (bf16 opart, R17) --------------
__global__ __launch_bounds__(256) void combine_kernel(const u16* __restrict__ opart,
                                                      const float* __restrict__ ml,
                                                      float* __restrict__ out) {
  const int tid = threadIdx.x;
  const int row = blockIdx.x * 16 + (tid >> 4);   // 0..16383
  const int d = (tid & 15) * 4;
  const int b = row >> 12;
  const int rowb = row & 4095;
  const int qg = rowb >> 4;
  const int r = rowb & 15;
  const int k2 = qg >> 6;
  const int nc = k2 + 1;
  const int sbase = b * 640 + 32 * k2 * (k2 + 1) + (qg & 63) * nc;

  float M = -INFINITY;
  float ms[4], ls[4];
  for (int cc = 0; cc < nc; cc++) {
    ms[cc] = ml[(size_t)(sbase + cc) * 32 + r * 2 + 0];
    ls[cc] = ml[(size_t)(sbase + cc) * 32 + r * 2 + 1];
    M = fmaxf(M, ms[cc]);
  }
  float L = 0.f;
  float4 acc = {0.f, 0.f, 0.f, 0.f};
  for (int cc = 0; cc < nc; cc++) {
    const float wgt = __expf(ms[cc] - M);
    L += ls[cc] * wgt;
    ushort4 ov = *(const ushort4*)(opart + (size_t)(sbase + cc) * 1024 + r * 64 + d);
    acc.x += bf2f(ov.x) * wgt; acc.y += bf2f(ov.y) * wgt;
    acc.z += bf2f(ov.z) * wgt; acc.w += bf2f(ov.w) * wgt;
  }
  const float inv = 1.0f / L;
  float4 res;
  res.x = rintf(acc.x * inv * 1.0e4f) * 1.0e-4f;
  res.y = rintf(acc.y * inv * 1.0e4f) * 1.0e-4f;
  res.z = rintf(acc.z * inv * 1.0e4f) * 1.0e-4f;
  res.w = rintf(acc.w * inv * 1.0e4f) * 1.0e-4f;
  *(float4*)(out + (size_t)row * AD + d) = res;
}

extern "C" void kernel_launch(void* const* d_in, const int* in_sizes, int n_in,
                              void* d_out, int out_size, void* d_ws, size_t ws_size,
                              hipStream_t stream) {
  const float* emb = (const float*)d_in[0];
  const float* Wq  = (const float*)d_in[1];
  const float* Wk  = (const float*)d_in[2];
  const float* Wv  = (const float*)d_in[3];
  float* out = (float*)d_out;

  char* ws = (char*)d_ws;
  u16* Wt = (u16*)ws;                               // 294912 B
  u16* Q  = (u16*)(ws + 294912);                    // 2 MiB each
  u16* K  = Q + (size_t)BS * AD;
  u16* Vt = K + (size_t)BS * AD;
  u16* opart = (u16*)(ws + 294912 + 3 * (size_t)BS * AD * 2);  // 2560*2KB bf16
  float* ml  = (float*)(ws + 294912 + 3 * (size_t)BS * AD * 2
                        + (size_t)2560 * 1024 * 2);            // 2560*128B

  wt_kernel<<<(3 * AD * EMB + 255) / 256, 256, 0, stream>>>(Wq, Wk, Wv, Wt);
  proj_kernel<<<BS / 32, 512, 0, stream>>>(emb, Wt, Q, K, Vt);
  flash_part<<<640, 256, 0, stream>>>(Q, K, Vt, opart, ml);
  combine_kernel<<<BS / 16, 256, 0, stream>>>(opart, ml, out);
}